// Round 2
// baseline (187.856 us; speedup 1.0000x reference)
//
#include <hip/hip_runtime.h>
#include <hip/hip_bf16.h>
#include <math.h>

// Problem constants (reference: B=32, P=256, D=64, T=4096, SCALE=1)
#define Bb 32
#define Pp 256
#define Dd 64
#define Tt 4096

typedef unsigned short ushort_t;
typedef __attribute__((ext_vector_type(8))) short bf16x8;   // 8 bf16 = 4 VGPRs
typedef __attribute__((ext_vector_type(4))) float f32x4;

#define TRIP_BYTES ((size_t)Bb * Pp * 64 * 16)   // 8,388,608
#define WS_NEED    TRIP_BYTES

// All logits live in the log2 domain: scores pre-scaled by log2(e) so every
// exp becomes a single v_exp_f32 (2^x). Softmax ratios are mathematically
// identical (softmax_t 2^{x_t} == softmax_t e^{x_t ln2}).
#define C2 (-0.7213475204444817f)   // -0.5 * log2(e)

__device__ __forceinline__ float fexp2(float x) {
#if __has_builtin(__builtin_amdgcn_exp2f)
  return __builtin_amdgcn_exp2f(x);
#else
  float r; asm("v_exp_f32 %0, %1" : "=v"(r) : "v"(x)); return r;
#endif
}

// ---- DPP row-local shuffle on the VALU pipe (R13-proven).
// ctrl: quad_perm xor1 = 0xB1, quad_perm xor2 = 0x4E,
//       row_half_mirror = 0x141 (cross-4 merge), row_mirror = 0x140 (cross-8).
template <int CTRL>
__device__ __forceinline__ float dppf(float x) {
  return __builtin_bit_cast(float,
      __builtin_amdgcn_update_dpp(0, __builtin_bit_cast(int, x), CTRL, 0xF, 0xF, true));
}

// R9-proven split-bf16 6-MFMA product (drops al*bl, ~2^-17 rel err)
__device__ __forceinline__ f32x4 mfma6(bf16x8 ah0, bf16x8 ah1, bf16x8 al0, bf16x8 al1,
                                       bf16x8 bh0, bf16x8 bh1, bf16x8 bl0, bf16x8 bl1) {
  f32x4 a = (f32x4)0.f;
  a = __builtin_amdgcn_mfma_f32_16x16x32_bf16(ah0, bh0, a, 0, 0, 0);
  a = __builtin_amdgcn_mfma_f32_16x16x32_bf16(ah1, bh1, a, 0, 0, 0);
  a = __builtin_amdgcn_mfma_f32_16x16x32_bf16(ah0, bl0, a, 0, 0, 0);
  a = __builtin_amdgcn_mfma_f32_16x16x32_bf16(al0, bh0, a, 0, 0, 0);
  a = __builtin_amdgcn_mfma_f32_16x16x32_bf16(ah1, bl1, a, 0, 0, 0);
  a = __builtin_amdgcn_mfma_f32_16x16x32_bf16(al1, bh1, a, 0, 0, 0);
  return a;
}

// In-register split-bf16 conversion: 8 floats -> hi bf16x8 + lo bf16x8.
// Same RNE hi + RNE residual as the old k_conv (numerics preserved).
__device__ __forceinline__ void cvt8(const float4 a, const float4 b,
                                     bf16x8* hi, bf16x8* lo) {
  float f[8] = {a.x, a.y, a.z, a.w, b.x, b.y, b.z, b.w};
  bf16x8 h, l;
#pragma unroll
  for (int j = 0; j < 8; ++j) {
    const __hip_bfloat16 hb = __float2bfloat16(f[j]);
    const float hf = __bfloat162float(hb);
    const __hip_bfloat16 lb = __float2bfloat16(f[j] - hf);
    h[j] = *(const short*)&hb;
    l[j] = *(const short*)&lb;
  }
  *hi = h; *lo = l;
}

struct TrueC  { static constexpr bool value = true;  };
struct FalseC { static constexpr bool value = false; };

// ==================== Phase 1: one-pass fused prefix-softmax ================
// R14: counters showed NO pipe >44% and Occupancy 16% -> latency-bound at
// 2 waves/SIMD (grid 512 = 2 blocks/CU was the limit, VGPR 80 allowed 4).
// Fixes:
//  (a) prefix-recompute split: each (b,strip) gets TWO blocks. half0 runs
//      sgs 0..SPLIT-1 full. half1 re-runs sgs 0..SPLIT-1 "light" (MFMA +
//      scores + R update only -> bitwise-identical prefix R, ~0.45x cost),
//      then sgs SPLIT..15 full. Grid 1024 -> 4 waves/SIMD.
//  (b) k_conv folded in: split-bf16 hi+lo is the same byte count as f32, so
//      A/B are loaded as float4 and converted in-register (cvt8). One fewer
//      kernel + no conv HBM round-trip. B converted once (sg-invariant).
//  (c) log2-domain logits: every __expf -> one v_exp_f32.
// Numerics otherwise identical to R13 (quad-exclusive prefix, batch softmax
// with exact in-lane max, per-wave exact M: argmax term 2^0=1 -> S>=1).
#define SPLIT 10
__global__ __launch_bounds__(256, 4) void k_main(const float* __restrict__ data,
                                                 const float* __restrict__ targets,
                                                 const float* __restrict__ task_pool,
                                                 float4* __restrict__ triples) {
  const int tid  = threadIdx.x;
  const int wid  = tid >> 6;
  const int lane = tid & 63;
  const int quad = lane >> 4;
  const int l16  = lane & 15;
  const int b     = blockIdx.x >> 5;
  const int sub   = blockIdx.x & 31;
  const int strip = sub >> 1;
  const int half  = sub & 1;
  const int t0    = strip * 256;
  const int wstrip = strip * 4 + wid;           // 0..63 (this wave's t-subset id)

  // ---- B fragments (sg-invariant): load f32, convert in-register.
  bf16x8 vbh0[4], vbh1[4], vbl0[4], vbl1[4];
#pragma unroll
  for (int nt = 0; nt < 4; ++nt) {
    const float* wr = task_pool + (size_t)(t0 + wid * 64 + nt * 16 + l16) * Dd + quad * 8;
    const float4 f0 = *(const float4*)(wr);
    const float4 f1 = *(const float4*)(wr + 4);
    const float4 f2 = *(const float4*)(wr + 32);
    const float4 f3 = *(const float4*)(wr + 36);
    cvt8(f0, f1, &vbh0[nt], &vbl0[nt]);
    cvt8(f2, f3, &vbh1[nt], &vbl1[nt]);
  }

  const float* arow = data + (size_t)b * Pp * Dd;
  const float* tgt  = targets + b * Pp;
  float4* __restrict__ trb = triples + (size_t)b * Pp * 64;

  float R[4];                                   // per-column running prefix (log2 domain)
#pragma unroll
  for (int nt = 0; nt < 4; ++nt) R[nt] = 0.f;

  // prologue: A fragments + targets for sg=0
  bf16x8 ah0, ah1, al0, al1;
  {
    const size_t a0 = (size_t)l16 * Dd + quad * 8;
    const float4 f0 = *(const float4*)(arow + a0);
    const float4 f1 = *(const float4*)(arow + a0 + 4);
    const float4 f2 = *(const float4*)(arow + a0 + 32);
    const float4 f3 = *(const float4*)(arow + a0 + 36);
    cvt8(f0, f1, &ah0, &al0);
    cvt8(f2, f3, &ah1, &al1);
  }
  float4 tq = *(const float4*)(tgt + quad * 4);

  auto step = [&](auto fullc, int sg) {
    constexpr bool FULL_ = decltype(fullc)::value;
    // ---- prefetch next sg's A floats (wraps at sg=15: harmless reload)
    const int pn = ((sg + 1) & 15) * 16;
    const size_t an = (size_t)(pn + l16) * Dd + quad * 8;
    const float4 nf0 = *(const float4*)(arow + an);
    const float4 nf1 = *(const float4*)(arow + an + 4);
    const float4 nf2 = *(const float4*)(arow + an + 32);
    const float4 nf3 = *(const float4*)(arow + an + 36);
    const float4 ntq = *(const float4*)(tgt + pn + quad * 4);

    float cc[4][4], av[4][4];
#pragma unroll
    for (int nt = 0; nt < 4; ++nt) {
      const f32x4 a = mfma6(ah0, ah1, al0, al1,
                            vbh0[nt], vbh1[nt], vbl0[nt], vbl1[nt]);
      float sc0, sc1, sc2, sc3;
      { const float e = tq.x - a[0]; sc0 = C2 * e * e; }
      { const float e = tq.y - a[1]; sc1 = C2 * e * e; }
      { const float e = tq.z - a[2]; sc2 = C2 * e * e; }
      { const float e = tq.w - a[3]; sc3 = C2 * e * e; }

      const float colsum = (sc0 + sc1) + (sc2 + sc3);
      const float x1 = __shfl_xor(colsum, 16, 64);
      const float x2 = __shfl_xor(colsum, 32, 64);
      const float x3 = __shfl_xor(x1, 32, 64);
      if (FULL_) {
        const float pre = (quad == 0) ? 0.f
                        : (quad == 1) ? x1
                        : (quad == 2) ? (x2 + x3)
                                      : (x1 + x2 + x3);
        const float base = R[nt] + pre;
        cc[nt][0] = base;
        cc[nt][1] = base + sc0;
        cc[nt][2] = cc[nt][1] + sc1;
        cc[nt][3] = cc[nt][2] + sc2;
        av[nt][0] = a[0]; av[nt][1] = a[1]; av[nt][2] = a[2]; av[nt][3] = a[3];
      }
      R[nt] += ((colsum + x1) + (x2 + x3));     // inclusive through this sg
    }

    if (FULL_) {
      // batch softmax over this lane's 4 columns, per p-row r
      float mm[4], ss[4], vv[4];
#pragma unroll
      for (int r = 0; r < 4; ++r) {
        const float m01 = fmaxf(cc[0][r], cc[1][r]);
        const float m23 = fmaxf(cc[2][r], cc[3][r]);
        mm[r] = fmaxf(m01, m23);
        float s = 0.f, v = 0.f;
#pragma unroll
        for (int nt = 0; nt < 4; ++nt) {
          const float e = fexp2(cc[nt][r] - mm[r]);
          s += e;
          v = fmaf(e, av[nt][r], v);
        }
        ss[r] = s; vv[r] = v;
      }

      // l16 butterfly on the VALU pipe via DPP (R13-proven)
      float M[4];
#pragma unroll
      for (int r = 0; r < 4; ++r) M[r] = mm[r];
#pragma unroll
      for (int r = 0; r < 4; ++r) M[r] = fmaxf(M[r], dppf<0xB1>(M[r]));   // xor1
#pragma unroll
      for (int r = 0; r < 4; ++r) M[r] = fmaxf(M[r], dppf<0x4E>(M[r]));   // xor2
#pragma unroll
      for (int r = 0; r < 4; ++r) M[r] = fmaxf(M[r], dppf<0x141>(M[r]));  // cross-4
#pragma unroll
      for (int r = 0; r < 4; ++r) M[r] = fmaxf(M[r], dppf<0x140>(M[r]));  // cross-8
#pragma unroll
      for (int r = 0; r < 4; ++r) {
        const float f = fexp2(mm[r] - M[r]);    // ==1 at the argmax lane
        ss[r] *= f; vv[r] *= f;
      }
#pragma unroll
      for (int r = 0; r < 4; ++r) { ss[r] += dppf<0xB1>(ss[r]);  vv[r] += dppf<0xB1>(vv[r]); }
#pragma unroll
      for (int r = 0; r < 4; ++r) { ss[r] += dppf<0x4E>(ss[r]);  vv[r] += dppf<0x4E>(vv[r]); }
#pragma unroll
      for (int r = 0; r < 4; ++r) { ss[r] += dppf<0x141>(ss[r]); vv[r] += dppf<0x141>(vv[r]); }
#pragma unroll
      for (int r = 0; r < 4; ++r) { ss[r] += dppf<0x140>(ss[r]); vv[r] += dppf<0x140>(vv[r]); }

      if (l16 == 0) {
#pragma unroll
        for (int r = 0; r < 4; ++r) {
          const int p = sg * 16 + quad * 4 + r;
          trb[p * 64 + wstrip] = make_float4(M[r], ss[r], vv[r], 0.f);
        }
      }
    }

    // convert prefetched A for next sg (latency already hidden under compute)
    cvt8(nf0, nf1, &ah0, &al0);
    cvt8(nf2, nf3, &ah1, &al1);
    tq = ntq;
  };

  if (half == 0) {
#pragma unroll 1
    for (int sg = 0; sg < SPLIT; ++sg) step(TrueC{}, sg);
  } else {
#pragma unroll 1
    for (int sg = 0; sg < SPLIT; ++sg) step(FalseC{}, sg);   // prefix recompute
#pragma unroll 1
    for (int sg = SPLIT; sg < 16; ++sg) step(TrueC{}, sg);
  }
}

// ==================== Phase 2: cross-strip merge (R6-proven, log2 domain) ===
__global__ __launch_bounds__(256) void k_merge(const float4* __restrict__ ws,
                                               float* __restrict__ out) {
  const int gt   = blockIdx.x * 256 + threadIdx.x;
  const int bp   = gt >> 6;
  const int lane = gt & 63;
  const float4 o = ws[(size_t)bp * 64 + lane];
  const float m = o.x, s = o.y, v = o.z;
  float M = m;
#pragma unroll
  for (int off = 32; off; off >>= 1) M = fmaxf(M, __shfl_xor(M, off, 64));
  const float f = fexp2(m - M);
  float S = f * s, V = f * v;
#pragma unroll
  for (int off = 32; off; off >>= 1) {
    S += __shfl_xor(S, off, 64);
    V += __shfl_xor(V, off, 64);
  }
  if (lane == 0) out[bp] = V / S;
}

// ============== Fallback (tiny ws): fused R1 structure + merge ==============
// (log2 domain to stay consistent with k_merge)
__global__ __launch_bounds__(256) void k_scan_fused(const float* __restrict__ data,
                                                    const float* __restrict__ targets,
                                                    const float* __restrict__ task_pool,
                                                    float4* __restrict__ ws) {
  const int b     = blockIdx.x >> 4;
  const int wid   = threadIdx.x >> 6;
  const int lane  = threadIdx.x & 63;
  const int chunk = ((blockIdx.x & 15) << 2) | wid;
  const int t     = (chunk << 6) | lane;
  float w[Dd];
#pragma unroll
  for (int d = 0; d < Dd; d += 4) {
    const float4 r = *(const float4*)(task_pool + (size_t)t * Dd + d);
    w[d] = r.x; w[d + 1] = r.y; w[d + 2] = r.z; w[d + 3] = r.w;
  }
  const float* drow = data + (size_t)b * (Pp * Dd);
  const float* tgt  = targets + b * Pp;
  float4* wsb       = ws + (size_t)b * (Pp * 64);
  float c = 0.f;
  for (int p = 0; p < Pp; ++p) {
    float a0 = 0.f, a1 = 0.f, a2 = 0.f, a3 = 0.f;
    const float* r = drow + p * Dd;
#pragma unroll
    for (int d = 0; d < Dd; d += 4) {
      a0 = fmaf(r[d], w[d], a0);         a1 = fmaf(r[d + 1], w[d + 1], a1);
      a2 = fmaf(r[d + 2], w[d + 2], a2); a3 = fmaf(r[d + 3], w[d + 3], a3);
    }
    const float pred = (a0 + a1) + (a2 + a3);
    float m = c;
#pragma unroll
    for (int off = 32; off; off >>= 1) m = fmaxf(m, __shfl_xor(m, off, 64));
    const float e = fexp2(c - m);
    float s = e, v = e * pred;
#pragma unroll
    for (int off = 32; off; off >>= 1) {
      s += __shfl_xor(s, off, 64);
      v += __shfl_xor(v, off, 64);
    }
    if (lane == 0) wsb[p * 64 + chunk] = make_float4(m, s, v, 0.f);
    const float err = tgt[p] - pred;
    c = fmaf(C2 * err, err, c);
  }
}

extern "C" void kernel_launch(void* const* d_in, const int* in_sizes, int n_in,
                              void* d_out, int out_size, void* d_ws, size_t ws_size,
                              hipStream_t stream) {
  const float* data      = (const float*)d_in[0];
  const float* targets   = (const float*)d_in[1];
  const float* task_pool = (const float*)d_in[2];
  float* out = (float*)d_out;

  float4* trips = (float4*)d_ws;   // 8.4 MB
  if (ws_size >= WS_NEED) {
    k_main <<<dim3(Bb * 32), dim3(256), 0, stream>>>(data, targets, task_pool, trips);
    k_merge<<<dim3((Bb * Pp * 64) / 256), dim3(256), 0, stream>>>(trips, out);
  } else {
    k_scan_fused<<<dim3(512), dim3(256), 0, stream>>>(data, targets, task_pool, trips);
    k_merge<<<dim3((Bb * Pp * 64) / 256), dim3(256), 0, stream>>>(trips, out);
  }
}

// Round 3
// 178.999 us; speedup vs baseline: 1.0495x; 1.0495x over previous
//
#include <hip/hip_runtime.h>
#include <hip/hip_bf16.h>
#include <math.h>

// Problem constants (reference: B=32, P=256, D=64, T=4096, SCALE=1)
#define Bb 32
#define Pp 256
#define Dd 64
#define Tt 4096

typedef unsigned short ushort_t;
typedef __attribute__((ext_vector_type(8))) short bf16x8;   // 8 bf16 = 4 VGPRs
typedef __attribute__((ext_vector_type(4))) float f32x4;

#define TRIP_BYTES ((size_t)Bb * Pp * 64 * 16)   // 8,388,608
#define A_BF_BYTES ((size_t)Bb * Pp * Dd * 2)    // 1,048,576 (each of hi/lo)
#define B_BF_BYTES ((size_t)Tt * Dd * 2)         //   524,288 (each of hi/lo)
#define WS_NEED    (TRIP_BYTES + 2 * A_BF_BYTES + 2 * B_BF_BYTES)

// Log2-domain logits (R14-validated, numerics passed): scores pre-scaled by
// log2(e) so every exp is a single v_exp_f32. Softmax ratios identical.
#define C2 (-0.7213475204444817f)   // -0.5 * log2(e)

__device__ __forceinline__ float fexp2(float x) {
  float r; asm("v_exp_f32 %0, %1" : "=v"(r) : "v"(x)); return r;
}

// ---- DPP row-local shuffle on the VALU pipe (R13-proven).
// ctrl: quad_perm xor1 = 0xB1, quad_perm xor2 = 0x4E,
//       row_half_mirror = 0x141 (cross-4 merge), row_mirror = 0x140 (cross-8).
template <int CTRL>
__device__ __forceinline__ float dppf(float x) {
  return __builtin_bit_cast(float,
      __builtin_amdgcn_update_dpp(0, __builtin_bit_cast(int, x), CTRL, 0xF, 0xF, true));
}

// R9-proven split-bf16 6-MFMA product (drops al*bl, ~2^-17 rel err)
__device__ __forceinline__ f32x4 mfma6(bf16x8 ah0, bf16x8 ah1, bf16x8 al0, bf16x8 al1,
                                       bf16x8 bh0, bf16x8 bh1, bf16x8 bl0, bf16x8 bl1) {
  f32x4 a = (f32x4)0.f;
  a = __builtin_amdgcn_mfma_f32_16x16x32_bf16(ah0, bh0, a, 0, 0, 0);
  a = __builtin_amdgcn_mfma_f32_16x16x32_bf16(ah1, bh1, a, 0, 0, 0);
  a = __builtin_amdgcn_mfma_f32_16x16x32_bf16(ah0, bl0, a, 0, 0, 0);
  a = __builtin_amdgcn_mfma_f32_16x16x32_bf16(al0, bh0, a, 0, 0, 0);
  a = __builtin_amdgcn_mfma_f32_16x16x32_bf16(ah1, bl1, a, 0, 0, 0);
  a = __builtin_amdgcn_mfma_f32_16x16x32_bf16(al1, bh1, a, 0, 0, 0);
  return a;
}

// =============== Phase 0: split-bf16 conversion of A and B ==================
// R15: RESTORED. R14 folded this into k_main via an in-register cvt8 with a
// float f[8] array inside a lambda -> compiler demoted conversion state +
// cc/av to scratch (FETCH 9MB->237MB, WRITE 8->90MB, k_main 42->135us).
// The separate pre-pass keeps k_main's loads as clean bf16x8 dwordx4.
__global__ __launch_bounds__(256) void k_conv(const float* __restrict__ data,
                                              const float* __restrict__ Wt,
                                              ushort_t* __restrict__ Ah, ushort_t* __restrict__ Al,
                                              ushort_t* __restrict__ Bh, ushort_t* __restrict__ Bl) {
  const int i  = blockIdx.x * 256 + threadIdx.x;
  const int NA = Bb * Pp * Dd;    // 524288
  const float x = (i < NA) ? data[i] : Wt[i - NA];
  const __hip_bfloat16 h = __float2bfloat16(x);
  const float hf = __bfloat162float(h);
  const __hip_bfloat16 l = __float2bfloat16(x - hf);
  if (i < NA) { Ah[i] = *(const ushort_t*)&h; Al[i] = *(const ushort_t*)&l; }
  else        { const int j = i - NA;
                Bh[j] = *(const ushort_t*)&h; Bl[j] = *(const ushort_t*)&l; }
}

// ==================== Phase 1: one-pass fused prefix-softmax ================
// R15 = R13 body (proven 42us, VGPR 80, zero scratch) + prefix-recompute
// split for occupancy (R14's valid idea, now spill-free):
//  - each (b,strip) gets TWO blocks. half0 runs sgs 0..SPLIT-1 full.
//    half1 re-runs sgs 0..SPLIT-1 "light" (MFMA + scores + R update only ->
//    bitwise-identical prefix R), then runs sgs SPLIT..15 full.
//  - grid 512 -> 1024 blocks; __launch_bounds__(256,4) -> 4 waves/SIMD
//    (R14 counters confirmed occupancy does double with this grid).
//  - step body is a template<bool FULL> __forceinline__ function, all state
//    by reference, every array index compile-time constant (no lambda, no
//    cvt arrays -> nothing for the compiler to demote to scratch).
//  - log2-domain exps (R14-validated numerics).
// Numerics per p-row identical to R13: quad-exclusive prefix, batch softmax
// with exact in-lane max, per-wave exact M (argmax term 2^0=1 -> S>=1).
#define SPLIT 10

template <bool FULL>
__device__ __forceinline__ void step_fn(
    int sg, int quad, int l16, int wstrip,
    const ushort_t* __restrict__ arow_base, const ushort_t* __restrict__ alow_base,
    const float* __restrict__ tgt, float4* __restrict__ trb,
    bf16x8& ah0, bf16x8& ah1, bf16x8& al0, bf16x8& al1, float4& tq,
    float (&R)[4],
    const bf16x8 (&vbh0)[4], const bf16x8 (&vbh1)[4],
    const bf16x8 (&vbl0)[4], const bf16x8 (&vbl1)[4]) {
  // ---- prefetch next sg's A-frags (wraps at sg=15: harmless L1-hot reload)
  const int pn = ((sg + 1) & 15) * 16;
  const size_t an = (size_t)(pn + l16) * Dd + quad * 8;
  const bf16x8 nah0 = *(const bf16x8*)(arow_base + an);
  const bf16x8 nah1 = *(const bf16x8*)(arow_base + an + 32);
  const bf16x8 nal0 = *(const bf16x8*)(alow_base + an);
  const bf16x8 nal1 = *(const bf16x8*)(alow_base + an + 32);
  const float4 ntq  = *(const float4*)(tgt + pn + quad * 4);

  float cc[4][4], av[4][4];
#pragma unroll
  for (int nt = 0; nt < 4; ++nt) {
    const f32x4 a = mfma6(ah0, ah1, al0, al1,
                          vbh0[nt], vbh1[nt], vbl0[nt], vbl1[nt]);
    float sc0, sc1, sc2, sc3;
    { const float e = tq.x - a[0]; sc0 = C2 * e * e; }
    { const float e = tq.y - a[1]; sc1 = C2 * e * e; }
    { const float e = tq.z - a[2]; sc2 = C2 * e * e; }
    { const float e = tq.w - a[3]; sc3 = C2 * e * e; }

    // quad-exclusive prefix of column sums (R11-proven; cross-row -> DS)
    const float colsum = (sc0 + sc1) + (sc2 + sc3);
    const float x1 = __shfl_xor(colsum, 16, 64);
    const float x2 = __shfl_xor(colsum, 32, 64);
    const float x3 = __shfl_xor(x1, 32, 64);
    if (FULL) {
      const float pre = (quad == 0) ? 0.f
                      : (quad == 1) ? x1
                      : (quad == 2) ? (x2 + x3)
                                    : (x1 + x2 + x3);
      const float base = R[nt] + pre;
      cc[nt][0] = base;
      cc[nt][1] = base + sc0;
      cc[nt][2] = cc[nt][1] + sc1;
      cc[nt][3] = cc[nt][2] + sc2;
      av[nt][0] = a[0]; av[nt][1] = a[1]; av[nt][2] = a[2]; av[nt][3] = a[3];
    }
    R[nt] += ((colsum + x1) + (x2 + x3));       // inclusive through this sg
  }

  if (FULL) {
    // batch softmax over this lane's 4 columns, per p-row r (exact in-lane max)
    float mm[4], ss[4], vv[4];
#pragma unroll
    for (int r = 0; r < 4; ++r) {
      const float m01 = fmaxf(cc[0][r], cc[1][r]);
      const float m23 = fmaxf(cc[2][r], cc[3][r]);
      mm[r] = fmaxf(m01, m23);
      float s = 0.f, v = 0.f;
#pragma unroll
      for (int nt = 0; nt < 4; ++nt) {
        const float e = fexp2(cc[nt][r] - mm[r]);
        s += e;
        v = fmaf(e, av[nt][r], v);
      }
      ss[r] = s; vv[r] = v;
    }

    // l16 butterfly on the VALU pipe via DPP (R13-proven): exact max rounds,
    // single rescale (==1 at the argmax lane -> S>=1, NaN-safe), sum rounds.
    float M[4];
#pragma unroll
    for (int r = 0; r < 4; ++r) M[r] = mm[r];
#pragma unroll
    for (int r = 0; r < 4; ++r) M[r] = fmaxf(M[r], dppf<0xB1>(M[r]));   // xor1
#pragma unroll
    for (int r = 0; r < 4; ++r) M[r] = fmaxf(M[r], dppf<0x4E>(M[r]));   // xor2
#pragma unroll
    for (int r = 0; r < 4; ++r) M[r] = fmaxf(M[r], dppf<0x141>(M[r]));  // cross-4
#pragma unroll
    for (int r = 0; r < 4; ++r) M[r] = fmaxf(M[r], dppf<0x140>(M[r]));  // cross-8
#pragma unroll
    for (int r = 0; r < 4; ++r) {
      const float f = fexp2(mm[r] - M[r]);
      ss[r] *= f; vv[r] *= f;
    }
#pragma unroll
    for (int r = 0; r < 4; ++r) { ss[r] += dppf<0xB1>(ss[r]);  vv[r] += dppf<0xB1>(vv[r]); }
#pragma unroll
    for (int r = 0; r < 4; ++r) { ss[r] += dppf<0x4E>(ss[r]);  vv[r] += dppf<0x4E>(vv[r]); }
#pragma unroll
    for (int r = 0; r < 4; ++r) { ss[r] += dppf<0x141>(ss[r]); vv[r] += dppf<0x141>(vv[r]); }
#pragma unroll
    for (int r = 0; r < 4; ++r) { ss[r] += dppf<0x140>(ss[r]); vv[r] += dppf<0x140>(vv[r]); }

    if (l16 == 0) {
#pragma unroll
      for (int r = 0; r < 4; ++r) {
        const int p = sg * 16 + quad * 4 + r;
        trb[p * 64 + wstrip] = make_float4(M[r], ss[r], vv[r], 0.f);
      }
    }
  }

  ah0 = nah0; ah1 = nah1; al0 = nal0; al1 = nal1; tq = ntq;
}

__global__ __launch_bounds__(256, 4) void k_main(const ushort_t* __restrict__ Ah,
                                                 const ushort_t* __restrict__ Al,
                                                 const ushort_t* __restrict__ Bh,
                                                 const ushort_t* __restrict__ Bl,
                                                 const float* __restrict__ targets,
                                                 float4* __restrict__ triples) {
  const int tid  = threadIdx.x;
  const int wid  = tid >> 6;
  const int lane = tid & 63;
  const int quad = lane >> 4;
  const int l16  = lane & 15;
  const int b     = blockIdx.x >> 5;
  const int sub   = blockIdx.x & 31;
  const int strip = sub >> 1;
  const int half  = sub & 1;
  const int t0    = strip * 256;
  const int wstrip = strip * 4 + wid;           // 0..63 (this wave's t-subset id)

  // ---- B fragments for this wave's 64 t-columns: VGPR-resident for all sgs.
  bf16x8 vbh0[4], vbh1[4], vbl0[4], vbl1[4];
#pragma unroll
  for (int nt = 0; nt < 4; ++nt) {
    const size_t boff = (size_t)(t0 + wid * 64 + nt * 16 + l16) * Dd + quad * 8;
    vbh0[nt] = *(const bf16x8*)(Bh + boff);
    vbh1[nt] = *(const bf16x8*)(Bh + boff + 32);
    vbl0[nt] = *(const bf16x8*)(Bl + boff);
    vbl1[nt] = *(const bf16x8*)(Bl + boff + 32);
  }

  const ushort_t* arow_base = Ah + (size_t)b * Pp * Dd;
  const ushort_t* alow_base = Al + (size_t)b * Pp * Dd;
  const float* tgt          = targets + b * Pp;
  float4* __restrict__ trb  = triples + (size_t)b * Pp * 64;

  float R[4];                                   // per-column running prefix (log2)
#pragma unroll
  for (int nt = 0; nt < 4; ++nt) R[nt] = 0.f;

  // prologue: A fragments + targets for sg=0
  const size_t aoff0 = (size_t)l16 * Dd + quad * 8;
  bf16x8 ah0 = *(const bf16x8*)(arow_base + aoff0);
  bf16x8 ah1 = *(const bf16x8*)(arow_base + aoff0 + 32);
  bf16x8 al0 = *(const bf16x8*)(alow_base + aoff0);
  bf16x8 al1 = *(const bf16x8*)(alow_base + aoff0 + 32);
  float4 tq  = *(const float4*)(tgt + quad * 4);

  if (half == 0) {
#pragma unroll 1
    for (int sg = 0; sg < SPLIT; ++sg)
      step_fn<true>(sg, quad, l16, wstrip, arow_base, alow_base, tgt, trb,
                    ah0, ah1, al0, al1, tq, R, vbh0, vbh1, vbl0, vbl1);
  } else {
#pragma unroll 1
    for (int sg = 0; sg < SPLIT; ++sg)       // prefix recompute (light)
      step_fn<false>(sg, quad, l16, wstrip, arow_base, alow_base, tgt, trb,
                     ah0, ah1, al0, al1, tq, R, vbh0, vbh1, vbl0, vbl1);
#pragma unroll 1
    for (int sg = SPLIT; sg < 16; ++sg)
      step_fn<true>(sg, quad, l16, wstrip, arow_base, alow_base, tgt, trb,
                    ah0, ah1, al0, al1, tq, R, vbh0, vbh1, vbl0, vbl1);
  }
}

// ==================== Phase 2: cross-strip merge (R6-proven, log2 domain) ===
__global__ __launch_bounds__(256) void k_merge(const float4* __restrict__ ws,
                                               float* __restrict__ out) {
  const int gt   = blockIdx.x * 256 + threadIdx.x;
  const int bp   = gt >> 6;
  const int lane = gt & 63;
  const float4 o = ws[(size_t)bp * 64 + lane];
  const float m = o.x, s = o.y, v = o.z;
  float M = m;
#pragma unroll
  for (int off = 32; off; off >>= 1) M = fmaxf(M, __shfl_xor(M, off, 64));
  const float f = fexp2(m - M);
  float S = f * s, V = f * v;
#pragma unroll
  for (int off = 32; off; off >>= 1) {
    S += __shfl_xor(S, off, 64);
    V += __shfl_xor(V, off, 64);
  }
  if (lane == 0) out[bp] = V / S;
}

// ============== Fallback (tiny ws): fused R1 structure + merge ==============
__global__ __launch_bounds__(256) void k_scan_fused(const float* __restrict__ data,
                                                    const float* __restrict__ targets,
                                                    const float* __restrict__ task_pool,
                                                    float4* __restrict__ ws) {
  const int b     = blockIdx.x >> 4;
  const int wid   = threadIdx.x >> 6;
  const int lane  = threadIdx.x & 63;
  const int chunk = ((blockIdx.x & 15) << 2) | wid;
  const int t     = (chunk << 6) | lane;
  float w[Dd];
#pragma unroll
  for (int d = 0; d < Dd; d += 4) {
    const float4 r = *(const float4*)(task_pool + (size_t)t * Dd + d);
    w[d] = r.x; w[d + 1] = r.y; w[d + 2] = r.z; w[d + 3] = r.w;
  }
  const float* drow = data + (size_t)b * (Pp * Dd);
  const float* tgt  = targets + b * Pp;
  float4* wsb       = ws + (size_t)b * (Pp * 64);
  float c = 0.f;
  for (int p = 0; p < Pp; ++p) {
    float a0 = 0.f, a1 = 0.f, a2 = 0.f, a3 = 0.f;
    const float* r = drow + p * Dd;
#pragma unroll
    for (int d = 0; d < Dd; d += 4) {
      a0 = fmaf(r[d], w[d], a0);         a1 = fmaf(r[d + 1], w[d + 1], a1);
      a2 = fmaf(r[d + 2], w[d + 2], a2); a3 = fmaf(r[d + 3], w[d + 3], a3);
    }
    const float pred = (a0 + a1) + (a2 + a3);
    float m = c;
#pragma unroll
    for (int off = 32; off; off >>= 1) m = fmaxf(m, __shfl_xor(m, off, 64));
    const float e = fexp2(c - m);
    float s = e, v = e * pred;
#pragma unroll
    for (int off = 32; off; off >>= 1) {
      s += __shfl_xor(s, off, 64);
      v += __shfl_xor(v, off, 64);
    }
    if (lane == 0) wsb[p * 64 + chunk] = make_float4(m, s, v, 0.f);
    const float err = tgt[p] - pred;
    c = fmaf(C2 * err, err, c);
  }
}

extern "C" void kernel_launch(void* const* d_in, const int* in_sizes, int n_in,
                              void* d_out, int out_size, void* d_ws, size_t ws_size,
                              hipStream_t stream) {
  const float* data      = (const float*)d_in[0];
  const float* targets   = (const float*)d_in[1];
  const float* task_pool = (const float*)d_in[2];
  float* out = (float*)d_out;

  if (ws_size >= WS_NEED) {
    float4*   trips = (float4*)d_ws;
    char*     cb    = (char*)d_ws + TRIP_BYTES;
    ushort_t* Ah    = (ushort_t*)cb;
    ushort_t* Al    = (ushort_t*)(cb + A_BF_BYTES);
    ushort_t* Bh    = (ushort_t*)(cb + 2 * A_BF_BYTES);
    ushort_t* Bl    = (ushort_t*)(cb + 2 * A_BF_BYTES + B_BF_BYTES);
    k_conv <<<dim3((Bb * Pp * Dd + Tt * Dd) / 256), dim3(256), 0, stream>>>(
        data, task_pool, Ah, Al, Bh, Bl);
    k_main <<<dim3(Bb * 32), dim3(256), 0, stream>>>(Ah, Al, Bh, Bl, targets, trips);
    k_merge<<<dim3((Bb * Pp * 64) / 256), dim3(256), 0, stream>>>(trips, out);
  } else {
    float4* triples = (float4*)d_ws;   // 8.4 MB
    k_scan_fused<<<dim3(512), dim3(256), 0, stream>>>(data, targets, task_pool, triples);
    k_merge<<<dim3((Bb * Pp * 64) / 256), dim3(256), 0, stream>>>(triples, out);
  }
}

// Round 4
// 106.779 us; speedup vs baseline: 1.7593x; 1.6764x over previous
//
#include <hip/hip_runtime.h>
#include <hip/hip_bf16.h>
#include <math.h>

// Problem constants (reference: B=32, P=256, D=64, T=4096, SCALE=1)
#define Bb 32
#define Pp 256
#define Dd 64
#define Tt 4096

typedef unsigned short ushort_t;
typedef __attribute__((ext_vector_type(8))) short bf16x8;   // 8 bf16 = 4 VGPRs
typedef __attribute__((ext_vector_type(4))) float f32x4;

// Partials: 128 per (b,p), each packed as float2(lm = m + log2(s), u = v/s).
// 8192 bp-rows * 128 * 8B = 8,388,608 — byte-identical to the old 64x16B.
#define TRIP_BYTES ((size_t)Bb * Pp * 128 * 8)
#define A_BF_BYTES ((size_t)Bb * Pp * Dd * 2)    // 1,048,576 (each of hi/lo)
#define B_BF_BYTES ((size_t)Tt * Dd * 2)         //   524,288 (each of hi/lo)
#define WS_NEED    (TRIP_BYTES + 2 * A_BF_BYTES + 2 * B_BF_BYTES)  // 11,534,336

// Log2-domain logits (R14-validated): one v_exp_f32 per exp; ratios identical.
#define C2 (-0.7213475204444817f)   // -0.5 * log2(e)

__device__ __forceinline__ float fexp2(float x) {
  float r; asm("v_exp_f32 %0, %1" : "=v"(r) : "v"(x)); return r;
}
__device__ __forceinline__ float flog2(float x) {
  float r; asm("v_log_f32 %0, %1" : "=v"(r) : "v"(x)); return r;
}
__device__ __forceinline__ float frcp(float x) {
  float r; asm("v_rcp_f32 %0, %1" : "=v"(r) : "v"(x)); return r;
}

// ---- DPP row-local shuffle on the VALU pipe (R13-proven).
// ctrl: quad_perm xor1 = 0xB1, quad_perm xor2 = 0x4E,
//       row_half_mirror = 0x141 (cross-4 merge), row_mirror = 0x140 (cross-8).
template <int CTRL>
__device__ __forceinline__ float dppf(float x) {
  return __builtin_bit_cast(float,
      __builtin_amdgcn_update_dpp(0, __builtin_bit_cast(int, x), CTRL, 0xF, 0xF, true));
}

// R9-proven split-bf16 6-MFMA product (drops al*bl, ~2^-17 rel err)
__device__ __forceinline__ f32x4 mfma6(bf16x8 ah0, bf16x8 ah1, bf16x8 al0, bf16x8 al1,
                                       bf16x8 bh0, bf16x8 bh1, bf16x8 bl0, bf16x8 bl1) {
  f32x4 a = (f32x4)0.f;
  a = __builtin_amdgcn_mfma_f32_16x16x32_bf16(ah0, bh0, a, 0, 0, 0);
  a = __builtin_amdgcn_mfma_f32_16x16x32_bf16(ah1, bh1, a, 0, 0, 0);
  a = __builtin_amdgcn_mfma_f32_16x16x32_bf16(ah0, bl0, a, 0, 0, 0);
  a = __builtin_amdgcn_mfma_f32_16x16x32_bf16(al0, bh0, a, 0, 0, 0);
  a = __builtin_amdgcn_mfma_f32_16x16x32_bf16(ah1, bl1, a, 0, 0, 0);
  a = __builtin_amdgcn_mfma_f32_16x16x32_bf16(al1, bh1, a, 0, 0, 0);
  return a;
}

// =============== Phase 0: split-bf16 conversion of A and B ==================
__global__ __launch_bounds__(256) void k_conv(const float* __restrict__ data,
                                              const float* __restrict__ Wt,
                                              ushort_t* __restrict__ Ah, ushort_t* __restrict__ Al,
                                              ushort_t* __restrict__ Bh, ushort_t* __restrict__ Bl) {
  const int i  = blockIdx.x * 256 + threadIdx.x;
  const int NA = Bb * Pp * Dd;    // 524288
  const float x = (i < NA) ? data[i] : Wt[i - NA];
  const __hip_bfloat16 h = __float2bfloat16(x);
  const float hf = __bfloat162float(h);
  const __hip_bfloat16 l = __float2bfloat16(x - hf);
  if (i < NA) { Ah[i] = *(const ushort_t*)&h; Al[i] = *(const ushort_t*)&l; }
  else        { const int j = i - NA;
                Bh[j] = *(const ushort_t*)&h; Bl[j] = *(const ushort_t*)&l; }
}

// ==================== Phase 1: one-pass fused prefix-softmax ================
// R16: R15's launch_bounds(256,4) spill post-mortem -> the 128-reg cap needs
// a body with HALF the per-wave state. Split along t (not sg): 32 strips of
// 128 t-columns per b, grid 1024; each wave owns 32 t (nt=2). Zero recompute
// (prefix R is per-t independent). B-frags 32 VGPRs, cc/av 16, no A
// prefetch -> peak live ~90 regs, fits the 4-waves/SIMD cap without spill.
// Partials compressed to float2(lm = M + log2(ss), u = vv/ss): 128 of them
// merge-exact vs the old (m,s,v) triple (out = sum 2^(lm-M) u / sum 2^(lm-M)).
// ss >= 1 always (exact-max M -> argmax column contributes 2^0 = 1).
// Softmax simplified: butterfly exact M FIRST, then one exp2 per column
// (no per-lane mm + rescale pass). Numerics per column identical.
__global__ __launch_bounds__(256, 4) void k_main(const ushort_t* __restrict__ Ah,
                                                 const ushort_t* __restrict__ Al,
                                                 const ushort_t* __restrict__ Bh,
                                                 const ushort_t* __restrict__ Bl,
                                                 const float* __restrict__ targets,
                                                 float2* __restrict__ trips) {
  const int tid  = threadIdx.x;
  const int wid  = tid >> 6;
  const int lane = tid & 63;
  const int quad = lane >> 4;
  const int l16  = lane & 15;
  const int b     = blockIdx.x >> 5;      // 32 blocks per b
  const int strip = blockIdx.x & 31;      // 128-t strip
  const int t0    = strip * 128;
  const int wstrip = strip * 4 + wid;     // 0..127 (this wave's 32-t subset id)

  // ---- B fragments for this wave's 32 t-columns (nt=0: rows +0, nt=1: +16)
  bf16x8 b0h0, b0h1, b0l0, b0l1, b1h0, b1h1, b1l0, b1l1;
  {
    const size_t r0 = (size_t)(t0 + wid * 32 + l16) * Dd + quad * 8;
    b0h0 = *(const bf16x8*)(Bh + r0);
    b0h1 = *(const bf16x8*)(Bh + r0 + 32);
    b0l0 = *(const bf16x8*)(Bl + r0);
    b0l1 = *(const bf16x8*)(Bl + r0 + 32);
    const size_t r1 = r0 + (size_t)16 * Dd;
    b1h0 = *(const bf16x8*)(Bh + r1);
    b1h1 = *(const bf16x8*)(Bh + r1 + 32);
    b1l0 = *(const bf16x8*)(Bl + r1);
    b1l1 = *(const bf16x8*)(Bl + r1 + 32);
  }

  const ushort_t* arow_base = Ah + (size_t)b * Pp * Dd;
  const ushort_t* alow_base = Al + (size_t)b * Pp * Dd;
  const float* tgt          = targets + b * Pp;
  float2* __restrict__ trb  = trips + (size_t)b * Pp * 128;

  float R0 = 0.f, R1 = 0.f;               // per-nt-column running prefix (log2)

#pragma unroll 1
  for (int sg = 0; sg < 16; ++sg) {
    const int p0 = sg * 16;
    // A fragments for rows p0..p0+15 (L1-hot: shared by all 4 waves; 4
    // waves/SIMD hide the load latency, no prefetch needed)
    const size_t aoff = (size_t)(p0 + l16) * Dd + quad * 8;
    const bf16x8 ah0 = *(const bf16x8*)(arow_base + aoff);
    const bf16x8 ah1 = *(const bf16x8*)(arow_base + aoff + 32);
    const bf16x8 al0 = *(const bf16x8*)(alow_base + aoff);
    const bf16x8 al1 = *(const bf16x8*)(alow_base + aoff + 32);
    const float4 tq  = *(const float4*)(tgt + p0 + quad * 4);

    const f32x4 a0 = mfma6(ah0, ah1, al0, al1, b0h0, b0h1, b0l0, b0l1);
    const f32x4 a1 = mfma6(ah0, ah1, al0, al1, b1h0, b1h1, b1l0, b1l1);

    // scores (log2 domain) + quad-exclusive prefix per nt column
    float cc0_0, cc0_1, cc0_2, cc0_3, cc1_0, cc1_1, cc1_2, cc1_3;
    {
      float s0, s1, s2, s3;
      { const float e = tq.x - a0[0]; s0 = C2 * e * e; }
      { const float e = tq.y - a0[1]; s1 = C2 * e * e; }
      { const float e = tq.z - a0[2]; s2 = C2 * e * e; }
      { const float e = tq.w - a0[3]; s3 = C2 * e * e; }
      const float colsum = (s0 + s1) + (s2 + s3);
      const float x1 = __shfl_xor(colsum, 16, 64);
      const float x2 = __shfl_xor(colsum, 32, 64);
      const float x3 = __shfl_xor(x1, 32, 64);
      const float pre = (quad == 0) ? 0.f
                      : (quad == 1) ? x1
                      : (quad == 2) ? (x2 + x3)
                                    : (x1 + x2 + x3);
      const float base = R0 + pre;
      cc0_0 = base;
      cc0_1 = base + s0;
      cc0_2 = cc0_1 + s1;
      cc0_3 = cc0_2 + s2;
      R0 += ((colsum + x1) + (x2 + x3));
    }
    {
      float s0, s1, s2, s3;
      { const float e = tq.x - a1[0]; s0 = C2 * e * e; }
      { const float e = tq.y - a1[1]; s1 = C2 * e * e; }
      { const float e = tq.z - a1[2]; s2 = C2 * e * e; }
      { const float e = tq.w - a1[3]; s3 = C2 * e * e; }
      const float colsum = (s0 + s1) + (s2 + s3);
      const float x1 = __shfl_xor(colsum, 16, 64);
      const float x2 = __shfl_xor(colsum, 32, 64);
      const float x3 = __shfl_xor(x1, 32, 64);
      const float pre = (quad == 0) ? 0.f
                      : (quad == 1) ? x1
                      : (quad == 2) ? (x2 + x3)
                                    : (x1 + x2 + x3);
      const float base = R1 + pre;
      cc1_0 = base;
      cc1_1 = base + s0;
      cc1_2 = cc1_1 + s1;
      cc1_3 = cc1_2 + s2;
      R1 += ((colsum + x1) + (x2 + x3));
    }

    // exact max over this wave's 32 t-columns, per p-row r: per-lane pair-max
    // then 4-round DPP butterfly (VALU pipe; R13-proven ctrl codes)
    float M[4];
    M[0] = fmaxf(cc0_0, cc1_0);
    M[1] = fmaxf(cc0_1, cc1_1);
    M[2] = fmaxf(cc0_2, cc1_2);
    M[3] = fmaxf(cc0_3, cc1_3);
#pragma unroll
    for (int r = 0; r < 4; ++r) M[r] = fmaxf(M[r], dppf<0xB1>(M[r]));   // xor1
#pragma unroll
    for (int r = 0; r < 4; ++r) M[r] = fmaxf(M[r], dppf<0x4E>(M[r]));   // xor2
#pragma unroll
    for (int r = 0; r < 4; ++r) M[r] = fmaxf(M[r], dppf<0x141>(M[r]));  // cross-4
#pragma unroll
    for (int r = 0; r < 4; ++r) M[r] = fmaxf(M[r], dppf<0x140>(M[r]));  // cross-8

    // single exp2 per column against the exact max (argmax term == 1)
    float ss[4], vv[4];
    {
      const float e0 = fexp2(cc0_0 - M[0]), e1 = fexp2(cc1_0 - M[0]);
      ss[0] = e0 + e1; vv[0] = fmaf(e0, a0[0], e1 * a1[0]);
    }
    {
      const float e0 = fexp2(cc0_1 - M[1]), e1 = fexp2(cc1_1 - M[1]);
      ss[1] = e0 + e1; vv[1] = fmaf(e0, a0[1], e1 * a1[1]);
    }
    {
      const float e0 = fexp2(cc0_2 - M[2]), e1 = fexp2(cc1_2 - M[2]);
      ss[2] = e0 + e1; vv[2] = fmaf(e0, a0[2], e1 * a1[2]);
    }
    {
      const float e0 = fexp2(cc0_3 - M[3]), e1 = fexp2(cc1_3 - M[3]);
      ss[3] = e0 + e1; vv[3] = fmaf(e0, a0[3], e1 * a1[3]);
    }

#pragma unroll
    for (int r = 0; r < 4; ++r) { ss[r] += dppf<0xB1>(ss[r]);  vv[r] += dppf<0xB1>(vv[r]); }
#pragma unroll
    for (int r = 0; r < 4; ++r) { ss[r] += dppf<0x4E>(ss[r]);  vv[r] += dppf<0x4E>(vv[r]); }
#pragma unroll
    for (int r = 0; r < 4; ++r) { ss[r] += dppf<0x141>(ss[r]); vv[r] += dppf<0x141>(vv[r]); }
#pragma unroll
    for (int r = 0; r < 4; ++r) { ss[r] += dppf<0x140>(ss[r]); vv[r] += dppf<0x140>(vv[r]); }

    if (l16 == 0) {
#pragma unroll
      for (int r = 0; r < 4; ++r) {
        const float lm = M[r] + flog2(ss[r]);     // ss >= 1 -> log2 safe
        const float u  = vv[r] * frcp(ss[r]);
        const int p = p0 + quad * 4 + r;
        trb[p * 128 + wstrip] = make_float2(lm, u);
      }
    }
  }
}

// ==================== Phase 2: cross-strip merge (128-wide, log2 domain) ====
// out = sum_j 2^(lm_j - M) u_j / sum_j 2^(lm_j - M)  — algebraically equal to
// the old (m,s,v) merge given lm = m + log2 s, u = v/s.
__global__ __launch_bounds__(256) void k_merge(const float2* __restrict__ ws,
                                               float* __restrict__ out) {
  const int bp   = blockIdx.x * 4 + (threadIdx.x >> 6);
  const int lane = threadIdx.x & 63;
  const float2 e0 = ws[(size_t)bp * 128 + lane];
  const float2 e1 = ws[(size_t)bp * 128 + 64 + lane];
  float M = fmaxf(e0.x, e1.x);
#pragma unroll
  for (int off = 32; off; off >>= 1) M = fmaxf(M, __shfl_xor(M, off, 64));
  const float f0 = fexp2(e0.x - M), f1 = fexp2(e1.x - M);
  float S = f0 + f1;
  float V = fmaf(f0, e0.y, f1 * e1.y);
#pragma unroll
  for (int off = 32; off; off >>= 1) {
    S += __shfl_xor(S, off, 64);
    V += __shfl_xor(V, off, 64);
  }
  if (lane == 0) out[bp] = V / S;
}

// ============== Fallback (tiny ws): fused R1 structure + merge ==============
// Writes real partials at [bp*128 + chunk] and neutral (lm=-1e30, u=0) at
// [bp*128 + 64 + chunk] so the 128-wide merge works unchanged.
__global__ __launch_bounds__(256) void k_scan_fused(const float* __restrict__ data,
                                                    const float* __restrict__ targets,
                                                    const float* __restrict__ task_pool,
                                                    float2* __restrict__ ws) {
  const int b     = blockIdx.x >> 4;
  const int wid   = threadIdx.x >> 6;
  const int lane  = threadIdx.x & 63;
  const int chunk = ((blockIdx.x & 15) << 2) | wid;
  const int t     = (chunk << 6) | lane;
  float w[Dd];
#pragma unroll
  for (int d = 0; d < Dd; d += 4) {
    const float4 r = *(const float4*)(task_pool + (size_t)t * Dd + d);
    w[d] = r.x; w[d + 1] = r.y; w[d + 2] = r.z; w[d + 3] = r.w;
  }
  const float* drow = data + (size_t)b * (Pp * Dd);
  const float* tgt  = targets + b * Pp;
  float2* wsb       = ws + (size_t)b * (Pp * 128);
  float c = 0.f;
  for (int p = 0; p < Pp; ++p) {
    float a0 = 0.f, a1 = 0.f, a2 = 0.f, a3 = 0.f;
    const float* r = drow + p * Dd;
#pragma unroll
    for (int d = 0; d < Dd; d += 4) {
      a0 = fmaf(r[d], w[d], a0);         a1 = fmaf(r[d + 1], w[d + 1], a1);
      a2 = fmaf(r[d + 2], w[d + 2], a2); a3 = fmaf(r[d + 3], w[d + 3], a3);
    }
    const float pred = (a0 + a1) + (a2 + a3);
    float m = c;
#pragma unroll
    for (int off = 32; off; off >>= 1) m = fmaxf(m, __shfl_xor(m, off, 64));
    const float e = fexp2(c - m);
    float s = e, v = e * pred;
#pragma unroll
    for (int off = 32; off; off >>= 1) {
      s += __shfl_xor(s, off, 64);
      v += __shfl_xor(v, off, 64);
    }
    if (lane == 0) {
      wsb[p * 128 + chunk]      = make_float2(m + flog2(s), v * frcp(s));
      wsb[p * 128 + 64 + chunk] = make_float2(-1e30f, 0.f);
    }
    const float err = tgt[p] - pred;
    c = fmaf(C2 * err, err, c);
  }
}

extern "C" void kernel_launch(void* const* d_in, const int* in_sizes, int n_in,
                              void* d_out, int out_size, void* d_ws, size_t ws_size,
                              hipStream_t stream) {
  const float* data      = (const float*)d_in[0];
  const float* targets   = (const float*)d_in[1];
  const float* task_pool = (const float*)d_in[2];
  float* out = (float*)d_out;

  if (ws_size >= WS_NEED) {
    float2*   trips = (float2*)d_ws;
    char*     cb    = (char*)d_ws + TRIP_BYTES;
    ushort_t* Ah    = (ushort_t*)cb;
    ushort_t* Al    = (ushort_t*)(cb + A_BF_BYTES);
    ushort_t* Bh    = (ushort_t*)(cb + 2 * A_BF_BYTES);
    ushort_t* Bl    = (ushort_t*)(cb + 2 * A_BF_BYTES + B_BF_BYTES);
    k_conv <<<dim3((Bb * Pp * Dd + Tt * Dd) / 256), dim3(256), 0, stream>>>(
        data, task_pool, Ah, Al, Bh, Bl);
    k_main <<<dim3(Bb * 32), dim3(256), 0, stream>>>(Ah, Al, Bh, Bl, targets, trips);
    k_merge<<<dim3((Bb * Pp) / 4), dim3(256), 0, stream>>>(trips, out);
  } else {
    float2* trips = (float2*)d_ws;   // 8.4 MB
    k_scan_fused<<<dim3(512), dim3(256), 0, stream>>>(data, targets, task_pool, trips);
    k_merge<<<dim3((Bb * Pp) / 4), dim3(256), 0, stream>>>(trips, out);
  }
}